// Round 1
// baseline (200.583 us; speedup 1.0000x reference)
//
#include <hip/hip_runtime.h>
#include <math.h>

// Problem constants (B, N, F_IN, E_DIM, F, T) = (4, 64, 32, 32, 64, 3)
#define Bv   4
#define Nv   64
#define FIN  32
#define EDIM 32
#define Fv   64
#define NN   (Nv*Nv)

__device__ __forceinline__ float sigmoidf_(float x) {
    return 1.f / (1.f + __expf(-x));
}

// H0 = relu(X @ W_embed + b_embed)   grid=B*N blocks, 64 threads
__global__ void embed_kernel(const float* __restrict__ X,
                             const float* __restrict__ W,
                             const float* __restrict__ bias,
                             float* __restrict__ H)
{
    const int bn = blockIdx.x;      // 0..255 = b*64+n
    const int f  = threadIdx.x;     // 0..63
    __shared__ float xs[FIN];
    if (f < FIN) xs[f] = X[bn*FIN + f];
    __syncthreads();
    float acc = bias[f];
    #pragma unroll
    for (int k = 0; k < FIN; ++k)
        acc = fmaf(xs[k], W[k*Fv + f], acc);
    H[bn*Fv + f] = fmaxf(acc, 0.f);
}

// One message-passing round, fully fused:
//   agg[n,i] = sum_{m: A[n,m]!=0} relu(E[n,m,:] @ W_edge[:, i*64+j] + b_edge) * Hin[m,j] summed over j
//   h1 = gru_step(0, Hin[n]);  Hout[n] = gru_step(h1, agg)
// grid = B*N blocks (one target node each), 256 threads = 4 waves.
__global__ __launch_bounds__(256) void round_kernel(
    const float* __restrict__ Hin, float* __restrict__ Hout,
    const float* __restrict__ A,  const float* __restrict__ E,
    const float* __restrict__ W_edge, const float* __restrict__ b_edge,
    const float* __restrict__ gk, const float* __restrict__ grk,
    const float* __restrict__ gb, const float* __restrict__ grb)
{
    const int bn   = blockIdx.x;
    const int b    = bn >> 6;
    const int n    = bn & 63;
    const int tid  = threadIdx.x;
    const int w    = tid >> 6;     // wave id 0..3
    const int lane = tid & 63;     // j index

    __shared__ float e_rows[Nv][EDIM];  // staged E rows for active edges (8 KB)
    __shared__ float h_src[Nv][Fv];     // staged source H rows (16 KB)
    __shared__ int   m_list[Nv];
    __shared__ int   cnt_s;
    __shared__ float agg[Fv];
    __shared__ float h_old[Fv];
    __shared__ float h1[Fv];
    __shared__ float xg[3*Fv];
    __shared__ float hg[3*Fv];

    // ---- build active-edge list (mask is block-uniform) ----
    if (tid == 0) {
        int c = 0;
        const float* arow = A + b*NN + n*Nv;
        for (int m = 0; m < Nv; ++m)
            if (arow[m] != 0.f) m_list[c++] = m;
        cnt_s = c;
    }
    __syncthreads();
    const int cnt = cnt_s;

    // ---- stage E rows + source H rows in LDS ----
    for (int idx = tid; idx < cnt*EDIM; idx += 256) {
        int a = idx >> 5, e = idx & 31;
        e_rows[a][e] = E[ (size_t)(b*NN + n*Nv + m_list[a])*EDIM + e ];
    }
    for (int idx = tid; idx < cnt*Fv; idx += 256) {
        int a = idx >> 6, j = idx & 63;
        h_src[a][j] = Hin[ (b*Nv + m_list[a])*Fv + j ];
    }
    if (tid < Fv) h_old[tid] = Hin[(b*Nv + n)*Fv + tid];
    __syncthreads();

    // ---- message phase: column-outer sweep of W_edge ----
    #pragma unroll 1
    for (int s = 0; s < 16; ++s) {
        const int i = w + 4*s;           // output feature row of the FxF matrix
        const int c = i*Fv + lane;       // flat column in [0,4096)
        float wc[EDIM];
        #pragma unroll
        for (int e = 0; e < EDIM; ++e) wc[e] = W_edge[e*4096 + c];
        const float be = b_edge[c];

        float sum = 0.f;
        int a = 0;
        for (; a + 1 < cnt; a += 2) {    // 2-way ILP on the dot chains
            float d0 = be, d1 = be;
            #pragma unroll
            for (int e = 0; e < EDIM; ++e) {
                d0 = fmaf(e_rows[a][e],   wc[e], d0);
                d1 = fmaf(e_rows[a+1][e], wc[e], d1);
            }
            sum = fmaf(fmaxf(d0, 0.f), h_src[a][lane],   sum);
            sum = fmaf(fmaxf(d1, 0.f), h_src[a+1][lane], sum);
        }
        if (a < cnt) {
            float d0 = be;
            #pragma unroll
            for (int e = 0; e < EDIM; ++e)
                d0 = fmaf(e_rows[a][e], wc[e], d0);
            sum = fmaf(fmaxf(d0, 0.f), h_src[a][lane], sum);
        }
        // reduce over the 64 j-lanes of this wave
        #pragma unroll
        for (int off = 32; off > 0; off >>= 1)
            sum += __shfl_down(sum, off);
        if (lane == 0) agg[i] = sum;
    }
    __syncthreads();

    // ---- GRU step 1: h = 0, x = h_old  (hg = recurrent bias only) ----
    if (tid < 3*Fv) {
        float acc = gb[tid];
        #pragma unroll
        for (int k = 0; k < Fv; ++k)
            acc = fmaf(h_old[k], gk[k*192 + tid], acc);
        xg[tid] = acc;
    }
    __syncthreads();
    if (tid < Fv) {
        float z    = sigmoidf_(xg[tid]       + grb[tid]);
        float r    = sigmoidf_(xg[64 + tid]  + grb[64 + tid]);
        float cand = tanhf    (xg[128 + tid] + r * grb[128 + tid]);
        h1[tid] = (1.f - z) * cand;          // z*h + (1-z)*cand with h=0
    }
    __syncthreads();

    // ---- GRU step 2: h = h1, x = agg ----
    if (tid < 3*Fv) {
        float ax = gb[tid], ah = grb[tid];
        #pragma unroll
        for (int k = 0; k < Fv; ++k) {
            ax = fmaf(agg[k], gk[k*192 + tid],  ax);
            ah = fmaf(h1[k],  grk[k*192 + tid], ah);
        }
        xg[tid] = ax; hg[tid] = ah;
    }
    __syncthreads();
    if (tid < Fv) {
        float z    = sigmoidf_(xg[tid]       + hg[tid]);
        float r    = sigmoidf_(xg[64 + tid]  + hg[64 + tid]);
        float cand = tanhf    (xg[128 + tid] + r * hg[128 + tid]);
        Hout[(b*Nv + n)*Fv + tid] = z * h1[tid] + (1.f - z) * cand;
    }
}

extern "C" void kernel_launch(void* const* d_in, const int* in_sizes, int n_in,
                              void* d_out, int out_size, void* d_ws, size_t ws_size,
                              hipStream_t stream)
{
    const float* X       = (const float*)d_in[0];
    const float* A       = (const float*)d_in[1];
    const float* E       = (const float*)d_in[2];
    const float* W_embed = (const float*)d_in[3];
    const float* b_embed = (const float*)d_in[4];
    const float* W_edge  = (const float*)d_in[5];
    const float* b_edge  = (const float*)d_in[6];
    const float* gk      = (const float*)d_in[7];
    const float* grk     = (const float*)d_in[8];
    const float* gb      = (const float*)d_in[9];
    const float* grb     = (const float*)d_in[10];
    float* out = (float*)d_out;

    float* H0 = (float*)d_ws;            // [B*N*F]
    float* H1 = H0 + Bv*Nv*Fv;

    embed_kernel<<<Bv*Nv, Fv, 0, stream>>>(X, W_embed, b_embed, H0);
    round_kernel<<<Bv*Nv, 256, 0, stream>>>(H0, H1, A, E, W_edge, b_edge, gk, grk, gb, grb);
    round_kernel<<<Bv*Nv, 256, 0, stream>>>(H1, H0, A, E, W_edge, b_edge, gk, grk, gb, grb);
    round_kernel<<<Bv*Nv, 256, 0, stream>>>(H0, out, A, E, W_edge, b_edge, gk, grk, gb, grb);
}

// Round 3
// 142.173 us; speedup vs baseline: 1.4108x; 1.4108x over previous
//
#include <hip/hip_runtime.h>
#include <math.h>

// Problem constants (B, N, F_IN, E_DIM, F, T) = (4, 64, 32, 32, 64, 3)
#define Bv   4
#define Nv   64
#define FIN  32
#define EDIM 32
#define Fv   64
#define NN   (Nv*Nv)

__device__ __forceinline__ float sigmoidf_(float x) {
    return 1.f / (1.f + __expf(-x));
}

// H0 = relu(X @ W_embed + b_embed)   grid=B*N blocks, 64 threads
__global__ void embed_kernel(const float* __restrict__ X,
                             const float* __restrict__ W,
                             const float* __restrict__ bias,
                             float* __restrict__ H)
{
    const int bn = blockIdx.x;      // 0..255 = b*64+n
    const int f  = threadIdx.x;     // 0..63
    __shared__ float xs[FIN];
    if (f < FIN) xs[f] = X[bn*FIN + f];
    __syncthreads();
    float acc = bias[f];
    #pragma unroll
    for (int k = 0; k < FIN; ++k)
        acc = fmaf(xs[k], W[k*Fv + f], acc);
    H[bn*Fv + f] = fmaxf(acc, 0.f);
}

// Message phase for one round.
// grid = (B*N, 4): block (bn, q) computes agg[bn, q*16 .. q*16+15].
// 256 threads = 4 waves; wave w handles slices i = q*16 + w*4 + s.
// E rows are read directly from global (uniform-address float4 -> one
// coalesced L1-hot request), keeping the LDS pipe for h_src only.
__global__ __launch_bounds__(256, 4) void msg_kernel(
    const float* __restrict__ Hin, const float* __restrict__ A,
    const float* __restrict__ E,  const float* __restrict__ W_edge,
    const float* __restrict__ b_edge, float* __restrict__ agg_g)
{
    const int bn   = blockIdx.x;
    const int q    = blockIdx.y;
    const int b    = bn >> 6;
    const int n    = bn & 63;
    const int tid  = threadIdx.x;
    const int w    = tid >> 6;     // wave id 0..3
    const int lane = tid & 63;     // j index

    __shared__ float h_src[Nv][Fv];     // staged source H rows (16 KB)
    __shared__ int   m_list[Nv];
    __shared__ int   cnt_s;

    // serial edge-list scan (proven deterministic in R1)
    if (tid == 0) {
        int c = 0;
        const float* arow = A + b*NN + n*Nv;
        for (int m = 0; m < Nv; ++m)
            if (arow[m] != 0.f) m_list[c++] = m;
        cnt_s = c;
    }
    __syncthreads();
    const int cnt = cnt_s;

    for (int idx = tid; idx < cnt*Fv; idx += 256) {
        int a = idx >> 6, j = idx & 63;
        h_src[a][j] = Hin[(b*Nv + m_list[a])*Fv + j];
    }
    __syncthreads();

    const float* Eb = E + (size_t)(b*NN + n*Nv)*EDIM;  // edge row m at Eb + m*EDIM

    #pragma unroll 1
    for (int s = 0; s < 4; ++s) {
        const int i = q*16 + w*4 + s;    // output feature row of the FxF matrix
        const int c = i*Fv + lane;       // flat column in [0,4096)
        float wc[EDIM];
        #pragma unroll
        for (int e = 0; e < EDIM; ++e) wc[e] = W_edge[e*4096 + c];
        const float be = b_edge[c];

        float sum = 0.f;
        int a = 0;
        for (; a + 1 < cnt; a += 2) {    // 2 independent dot chains
            const float4* e0 = (const float4*)(Eb + (size_t)m_list[a]   * EDIM);
            const float4* e1 = (const float4*)(Eb + (size_t)m_list[a+1] * EDIM);
            float d0 = be, d1 = be;
            #pragma unroll
            for (int t = 0; t < 8; ++t) {
                const float4 x0 = e0[t];
                const float4 x1 = e1[t];
                d0 = fmaf(x0.x, wc[4*t],   d0);
                d0 = fmaf(x0.y, wc[4*t+1], d0);
                d0 = fmaf(x0.z, wc[4*t+2], d0);
                d0 = fmaf(x0.w, wc[4*t+3], d0);
                d1 = fmaf(x1.x, wc[4*t],   d1);
                d1 = fmaf(x1.y, wc[4*t+1], d1);
                d1 = fmaf(x1.z, wc[4*t+2], d1);
                d1 = fmaf(x1.w, wc[4*t+3], d1);
            }
            sum = fmaf(fmaxf(d0, 0.f), h_src[a][lane],   sum);
            sum = fmaf(fmaxf(d1, 0.f), h_src[a+1][lane], sum);
        }
        if (a < cnt) {
            const float4* e0 = (const float4*)(Eb + (size_t)m_list[a] * EDIM);
            float d0 = be;
            #pragma unroll
            for (int t = 0; t < 8; ++t) {
                const float4 x0 = e0[t];
                d0 = fmaf(x0.x, wc[4*t],   d0);
                d0 = fmaf(x0.y, wc[4*t+1], d0);
                d0 = fmaf(x0.z, wc[4*t+2], d0);
                d0 = fmaf(x0.w, wc[4*t+3], d0);
            }
            sum = fmaf(fmaxf(d0, 0.f), h_src[a][lane], sum);
        }
        // reduce over the 64 j-lanes of this wave
        #pragma unroll
        for (int off = 32; off > 0; off >>= 1)
            sum += __shfl_down(sum, off);
        if (lane == 0) agg_g[bn*Fv + i] = sum;
    }
}

// Both GRU steps for one round. grid = B*N blocks, 192 threads (3 waves).
__global__ __launch_bounds__(192) void gru_kernel(
    const float* __restrict__ Hin, const float* __restrict__ agg_g,
    float* __restrict__ Hout,
    const float* __restrict__ gk, const float* __restrict__ grk,
    const float* __restrict__ gb, const float* __restrict__ grb)
{
    const int bn  = blockIdx.x;
    const int tid = threadIdx.x;   // 0..191

    __shared__ float h_old[Fv];
    __shared__ float aggs[Fv];
    __shared__ float h1[Fv];
    __shared__ float xg[3*Fv];
    __shared__ float hg[3*Fv];

    if (tid < Fv) {
        h_old[tid] = Hin[bn*Fv + tid];
        aggs[tid]  = agg_g[bn*Fv + tid];
    }
    __syncthreads();

    // step 1: h = 0, x = h_old  (recurrent side is just the bias)
    {
        float acc = gb[tid];
        #pragma unroll
        for (int k = 0; k < Fv; ++k)
            acc = fmaf(h_old[k], gk[k*192 + tid], acc);
        xg[tid] = acc;
    }
    __syncthreads();
    if (tid < Fv) {
        float z    = sigmoidf_(xg[tid]       + grb[tid]);
        float r    = sigmoidf_(xg[64 + tid]  + grb[64 + tid]);
        float cand = tanhf    (xg[128 + tid] + r * grb[128 + tid]);
        h1[tid] = (1.f - z) * cand;          // z*h + (1-z)*cand with h=0
    }
    __syncthreads();

    // step 2: h = h1, x = agg
    {
        float ax = gb[tid], ah = grb[tid];
        #pragma unroll
        for (int k = 0; k < Fv; ++k) {
            ax = fmaf(aggs[k], gk[k*192 + tid],  ax);
            ah = fmaf(h1[k],   grk[k*192 + tid], ah);
        }
        xg[tid] = ax; hg[tid] = ah;
    }
    __syncthreads();
    if (tid < Fv) {
        float z    = sigmoidf_(xg[tid]       + hg[tid]);
        float r    = sigmoidf_(xg[64 + tid]  + hg[64 + tid]);
        float cand = tanhf    (xg[128 + tid] + r * hg[128 + tid]);
        Hout[bn*Fv + tid] = z * h1[tid] + (1.f - z) * cand;
    }
}

extern "C" void kernel_launch(void* const* d_in, const int* in_sizes, int n_in,
                              void* d_out, int out_size, void* d_ws, size_t ws_size,
                              hipStream_t stream)
{
    const float* X       = (const float*)d_in[0];
    const float* A       = (const float*)d_in[1];
    const float* E       = (const float*)d_in[2];
    const float* W_embed = (const float*)d_in[3];
    const float* b_embed = (const float*)d_in[4];
    const float* W_edge  = (const float*)d_in[5];
    const float* b_edge  = (const float*)d_in[6];
    const float* gk      = (const float*)d_in[7];
    const float* grk     = (const float*)d_in[8];
    const float* gb      = (const float*)d_in[9];
    const float* grb     = (const float*)d_in[10];
    float* out = (float*)d_out;

    float* H0 = (float*)d_ws;            // [B*N*F]
    float* H1 = H0 + Bv*Nv*Fv;           // ws total: 128 KB (same as R1)

    const dim3 mgrid(Bv*Nv, 4);

    embed_kernel<<<Bv*Nv, Fv, 0, stream>>>(X, W_embed, b_embed, H0);

    // round 1: H0 -> H1, agg scratch = out (dead until the end)
    msg_kernel<<<mgrid, 256, 0, stream>>>(H0, A, E, W_edge, b_edge, out);
    gru_kernel<<<Bv*Nv, 192, 0, stream>>>(H0, out, H1, gk, grk, gb, grb);
    // round 2: H1 -> H0, agg scratch = out
    msg_kernel<<<mgrid, 256, 0, stream>>>(H1, A, E, W_edge, b_edge, out);
    gru_kernel<<<Bv*Nv, 192, 0, stream>>>(H1, out, H0, gk, grk, gb, grb);
    // round 3: H0 -> out, agg scratch = H1 (dead after round 2)
    msg_kernel<<<mgrid, 256, 0, stream>>>(H0, A, E, W_edge, b_edge, H1);
    gru_kernel<<<Bv*Nv, 192, 0, stream>>>(H0, H1, out, gk, grk, gb, grb);
}

// Round 4
// 66.292 us; speedup vs baseline: 3.0258x; 2.1447x over previous
//
#include <hip/hip_runtime.h>
#include <math.h>

// Problem constants (B, N, F_IN, E_DIM, F, T) = (4, 64, 32, 32, 64, 3)
#define Bv   4
#define Nv   64
#define FIN  32
#define EDIM 32
#define Fv   64
#define NN   (Nv*Nv)

typedef __bf16 bf16x8 __attribute__((ext_vector_type(8)));
typedef float  f32x4  __attribute__((ext_vector_type(4)));

__device__ __forceinline__ float sigmoidf_(float x) {
    return 1.f / (1.f + __expf(-x));
}

__device__ __forceinline__ bf16x8 zero8() {
    bf16x8 v;
    #pragma unroll
    for (int t = 0; t < 8; ++t) v[t] = (__bf16)0.f;
    return v;
}

// One-time: W_edge f32[32][4096] -> bf16 B-fragments.
// Fragment layout for mfma_f32_16x16x32_bf16 B-operand:
//   lane l holds B[k=(l>>4)*8+t][col=nt*16+(l&15)], t=0..7  (16B per lane)
// Wf[nt*64 + lane][8]
__global__ void prep_w_kernel(const float* __restrict__ W_edge,
                              __bf16* __restrict__ Wf)
{
    const int nt   = blockIdx.x;    // 0..255 N-tile
    const int lane = threadIdx.x;   // 0..63
    const int kb   = (lane >> 4) * 8;
    const int c    = nt*16 + (lane & 15);
    bf16x8 v;
    #pragma unroll
    for (int t = 0; t < 8; ++t)
        v[t] = (__bf16)W_edge[(kb + t)*4096 + c];
    *(bf16x8*)(Wf + ((size_t)(nt*64 + lane))*8) = v;
}

// H0 = relu(X @ W_embed + b_embed)   grid=B*N blocks, 64 threads
__global__ void embed_kernel(const float* __restrict__ X,
                             const float* __restrict__ W,
                             const float* __restrict__ bias,
                             float* __restrict__ H)
{
    const int bn = blockIdx.x;
    const int f  = threadIdx.x;
    __shared__ float xs[FIN];
    if (f < FIN) xs[f] = X[bn*FIN + f];
    __syncthreads();
    float acc = bias[f];
    #pragma unroll
    for (int k = 0; k < FIN; ++k)
        acc = fmaf(xs[k], W[k*Fv + f], acc);
    H[bn*Fv + f] = fmaxf(acc, 0.f);
}

// Message phase via MFMA.
// grid = (B*N, 4): block (bn,q) computes agg[bn, q*16 .. q*16+15].
// 256 threads = 4 waves; wave w handles i = q*16 + w*4 + {0..3}.
// Per (i, nt-subtile, M-tile): one mfma_f32_16x16x32_bf16 computes the
// [16 edges x 16 cols] relu-input tile; epilogue multiplies by h_src and
// accumulates; per-i wave reduce writes agg.
__global__ __launch_bounds__(256) void msg_kernel(
    const float* __restrict__ Hin, const float* __restrict__ A,
    const float* __restrict__ E,  const __bf16* __restrict__ Wf,
    const float* __restrict__ b_edge, float* __restrict__ agg_g)
{
    const int bn   = blockIdx.x;
    const int q    = blockIdx.y;
    const int b    = bn >> 6;
    const int n    = bn & 63;
    const int tid  = threadIdx.x;
    const int w    = tid >> 6;
    const int lane = tid & 63;

    __shared__ float h_src[Nv][66];   // stride 66: epilogue reads ~2-way max
    __shared__ int   m_list[Nv];
    __shared__ int   cnt_s;

    // serial edge-list scan (proven deterministic)
    if (tid == 0) {
        int c = 0;
        const float* arow = A + b*NN + n*Nv;
        for (int m = 0; m < Nv; ++m)
            if (arow[m] != 0.f) m_list[c++] = m;
        cnt_s = c;
    }
    __syncthreads();
    const int cnt = cnt_s;
    const int pad = (cnt + 15) & ~15;   // M padded to 16
    const int Mt  = pad >> 4;           // 0..4 M-tiles (wave-uniform)

    // stage source H rows; zero the pad rows (kills pad-row contributions)
    for (int idx = tid; idx < pad*Fv; idx += 256) {
        int a = idx >> 6, j = idx & 63;
        h_src[a][j] = (a < cnt) ? Hin[(b*Nv + m_list[a])*Fv + j] : 0.f;
    }
    __syncthreads();

    // ---- build A fragments (lane l: row = l&15, k = (l>>4)*8 + t) ----
    const int arow_loc = lane & 15;
    const int kb       = (lane >> 4) * 8;
    bf16x8 af0 = zero8(), af1 = zero8(), af2 = zero8(), af3 = zero8();
    #define BUILD_AF(AF, MT)                                                  \
    if ((MT) < Mt) {                                                          \
        const int a = (MT)*16 + arow_loc;                                     \
        if (a < cnt) {                                                        \
            const float* er = E + ((size_t)(b*NN + n*Nv + m_list[a]))*EDIM + kb; \
            const float4 x0 = *(const float4*)er;                             \
            const float4 x1 = *(const float4*)(er + 4);                       \
            AF[0]=(__bf16)x0.x; AF[1]=(__bf16)x0.y;                           \
            AF[2]=(__bf16)x0.z; AF[3]=(__bf16)x0.w;                           \
            AF[4]=(__bf16)x1.x; AF[5]=(__bf16)x1.y;                           \
            AF[6]=(__bf16)x1.z; AF[7]=(__bf16)x1.w;                           \
        }                                                                     \
    }
    BUILD_AF(af0, 0) BUILD_AF(af1, 1) BUILD_AF(af2, 2) BUILD_AF(af3, 3)
    #undef BUILD_AF

    const int c16 = lane & 15;
    const int rg  = (lane >> 4) * 4;    // C-layout row group

    #pragma unroll 1
    for (int s = 0; s < 4; ++s) {
        const int i = q*16 + w*4 + s;
        float part = 0.f;
        #pragma unroll
        for (int u = 0; u < 4; ++u) {
            const int nt = i*4 + u;
            const bf16x8 bf = *(const bf16x8*)(Wf + ((size_t)(nt*64 + lane))*8);
            const float  be = b_edge[nt*16 + c16];
            const int    j  = u*16 + c16;        // col within h_src row
            f32x4 z; z[0]=0.f; z[1]=0.f; z[2]=0.f; z[3]=0.f;
            #define DO_MT(AF, MT)                                             \
            if ((MT) < Mt) {                                                  \
                f32x4 d = __builtin_amdgcn_mfma_f32_16x16x32_bf16(AF, bf, z, 0, 0, 0); \
                const int ab = (MT)*16 + rg;                                  \
                part = fmaf(fmaxf(d[0] + be, 0.f), h_src[ab+0][j], part);     \
                part = fmaf(fmaxf(d[1] + be, 0.f), h_src[ab+1][j], part);     \
                part = fmaf(fmaxf(d[2] + be, 0.f), h_src[ab+2][j], part);     \
                part = fmaf(fmaxf(d[3] + be, 0.f), h_src[ab+3][j], part);     \
            }
            DO_MT(af0, 0) DO_MT(af1, 1) DO_MT(af2, 2) DO_MT(af3, 3)
            #undef DO_MT
        }
        // reduce over the wave's 64 lanes
        #pragma unroll
        for (int off = 32; off > 0; off >>= 1)
            part += __shfl_xor(part, off);
        if (lane == 0) agg_g[bn*Fv + i] = part;
    }
}

// Both GRU steps for one round. grid = B*N blocks, 192 threads (3 waves).
__global__ __launch_bounds__(192) void gru_kernel(
    const float* __restrict__ Hin, const float* __restrict__ agg_g,
    float* __restrict__ Hout,
    const float* __restrict__ gk, const float* __restrict__ grk,
    const float* __restrict__ gb, const float* __restrict__ grb)
{
    const int bn  = blockIdx.x;
    const int tid = threadIdx.x;   // 0..191

    __shared__ float h_old[Fv];
    __shared__ float aggs[Fv];
    __shared__ float h1[Fv];
    __shared__ float xg[3*Fv];
    __shared__ float hg[3*Fv];

    if (tid < Fv) {
        h_old[tid] = Hin[bn*Fv + tid];
        aggs[tid]  = agg_g[bn*Fv + tid];
    }
    __syncthreads();

    // step 1: h = 0, x = h_old  (recurrent side is just the bias)
    {
        float acc = gb[tid];
        #pragma unroll
        for (int k = 0; k < Fv; ++k)
            acc = fmaf(h_old[k], gk[k*192 + tid], acc);
        xg[tid] = acc;
    }
    __syncthreads();
    if (tid < Fv) {
        float z    = sigmoidf_(xg[tid]       + grb[tid]);
        float r    = sigmoidf_(xg[64 + tid]  + grb[64 + tid]);
        float cand = tanhf    (xg[128 + tid] + r * grb[128 + tid]);
        h1[tid] = (1.f - z) * cand;          // z*h + (1-z)*cand with h=0
    }
    __syncthreads();

    // step 2: h = h1, x = agg
    {
        float ax = gb[tid], ah = grb[tid];
        #pragma unroll
        for (int k = 0; k < Fv; ++k) {
            ax = fmaf(aggs[k], gk[k*192 + tid],  ax);
            ah = fmaf(h1[k],   grk[k*192 + tid], ah);
        }
        xg[tid] = ax; hg[tid] = ah;
    }
    __syncthreads();
    if (tid < Fv) {
        float z    = sigmoidf_(xg[tid]       + hg[tid]);
        float r    = sigmoidf_(xg[64 + tid]  + hg[64 + tid]);
        float cand = tanhf    (xg[128 + tid] + r * hg[128 + tid]);
        Hout[bn*Fv + tid] = z * h1[tid] + (1.f - z) * cand;
    }
}

extern "C" void kernel_launch(void* const* d_in, const int* in_sizes, int n_in,
                              void* d_out, int out_size, void* d_ws, size_t ws_size,
                              hipStream_t stream)
{
    const float* X       = (const float*)d_in[0];
    const float* A       = (const float*)d_in[1];
    const float* E       = (const float*)d_in[2];
    const float* W_embed = (const float*)d_in[3];
    const float* b_embed = (const float*)d_in[4];
    const float* W_edge  = (const float*)d_in[5];
    const float* b_edge  = (const float*)d_in[6];
    const float* gk      = (const float*)d_in[7];
    const float* grk     = (const float*)d_in[8];
    const float* gb      = (const float*)d_in[9];
    const float* grb     = (const float*)d_in[10];
    float* out = (float*)d_out;

    float*  H0 = (float*)d_ws;                 // 64 KB
    float*  H1 = H0 + Bv*Nv*Fv;                // 64 KB
    __bf16* Wf = (__bf16*)(H1 + Bv*Nv*Fv);     // 256 KB (ws total 384 KB)

    const dim3 mgrid(Bv*Nv, 4);

    prep_w_kernel<<<256, 64, 0, stream>>>(W_edge, Wf);
    embed_kernel<<<Bv*Nv, Fv, 0, stream>>>(X, W_embed, b_embed, H0);

    // round 1: H0 -> H1, agg scratch = out (dead until the end)
    msg_kernel<<<mgrid, 256, 0, stream>>>(H0, A, E, Wf, b_edge, out);
    gru_kernel<<<Bv*Nv, 192, 0, stream>>>(H0, out, H1, gk, grk, gb, grb);
    // round 2: H1 -> H0, agg scratch = out
    msg_kernel<<<mgrid, 256, 0, stream>>>(H1, A, E, Wf, b_edge, out);
    gru_kernel<<<Bv*Nv, 192, 0, stream>>>(H1, out, H0, gk, grk, gb, grb);
    // round 3: H0 -> out, agg scratch = H1 (dead after round 2)
    msg_kernel<<<mgrid, 256, 0, stream>>>(H0, A, E, Wf, b_edge, H1);
    gru_kernel<<<Bv*Nv, 192, 0, stream>>>(H0, H1, out, gk, grk, gb, grb);
}

// Round 5
// 49.810 us; speedup vs baseline: 4.0270x; 1.3309x over previous
//
#include <hip/hip_runtime.h>
#include <math.h>

// Problem constants (B, N, F_IN, E_DIM, F, T) = (4, 64, 32, 32, 64, 3)
#define Bv   4
#define Nv   64
#define FIN  32
#define EDIM 32
#define Fv   64
#define NN   (Nv*Nv)

typedef __bf16 bf16x8 __attribute__((ext_vector_type(8)));
typedef float  f32x4  __attribute__((ext_vector_type(4)));

__device__ __forceinline__ float sigmoidf_(float x) {
    return 1.f / (1.f + __expf(-x));
}

// ---------------------------------------------------------------------------
// One-time prep, fused: grid 768 x 64 threads.
//   blk <  256 : W_edge -> bf16 B-fragments   Wf[nt*64+lane][8]
//   blk <  512 : per-node edge list + E -> bf16 rows (zero-padded) Ebf
//   blk >= 512 : embed  H0 = relu(X @ W_embed + b_embed)
// B-fragment layout (mfma_f32_16x16x32_bf16): lane l holds
//   B[k=(l>>4)*8+t][col=nt*16+(l&15)], t=0..7.
// Ebf row-major [bn][64][32] bf16, row a = E[bn, m_list[a]] (a<cnt) else 0;
// A-fragment for M-tile mt is then a 16B load at row mt*16+(l&15), k-block
// (l>>4)*8 — perfectly coalesced.
// ---------------------------------------------------------------------------
__global__ __launch_bounds__(64) void prep_kernel(
    const float* __restrict__ X, const float* __restrict__ W_embed,
    const float* __restrict__ b_embed, const float* __restrict__ A,
    const float* __restrict__ E, const float* __restrict__ W_edge,
    float* __restrict__ H0, __bf16* __restrict__ Wf,
    __bf16* __restrict__ Ebf, int* __restrict__ m_list_g,
    int* __restrict__ cnt_g)
{
    const int blk  = blockIdx.x;
    const int lane = threadIdx.x;

    if (blk < 256) {                       // ---- W_edge fragments ----
        const int nt = blk;
        const int kb = (lane >> 4) * 8;
        const int c  = nt*16 + (lane & 15);
        bf16x8 v;
        #pragma unroll
        for (int t = 0; t < 8; ++t)
            v[t] = (__bf16)W_edge[(kb + t)*4096 + c];
        *(bf16x8*)(Wf + ((size_t)(nt*64 + lane))*8) = v;
    } else if (blk < 512) {                // ---- edge list + E rows ----
        const int bn = blk - 256;
        const int b  = bn >> 6;
        const int n  = bn & 63;
        __shared__ int ml[Nv];
        __shared__ int cnt_s;
        if (lane == 0) {                   // serial scan: once, off hot path
            int c = 0;
            const float* arow = A + b*NN + n*Nv;
            for (int m = 0; m < Nv; ++m)
                if (arow[m] != 0.f) ml[c++] = m;
            cnt_s = c;
        }
        __syncthreads();
        const int cnt = cnt_s;
        m_list_g[bn*64 + lane] = (lane < cnt) ? ml[lane] : 0;
        if (lane == 0) cnt_g[bn] = cnt;
        __bf16 row[EDIM];
        if (lane < cnt) {
            const float* er = E + ((size_t)(b*NN + n*Nv + ml[lane]))*EDIM;
            #pragma unroll
            for (int t = 0; t < 8; ++t) {
                const float4 x = *(const float4*)(er + 4*t);
                row[4*t  ] = (__bf16)x.x; row[4*t+1] = (__bf16)x.y;
                row[4*t+2] = (__bf16)x.z; row[4*t+3] = (__bf16)x.w;
            }
        } else {
            #pragma unroll
            for (int e = 0; e < EDIM; ++e) row[e] = (__bf16)0.f;
        }
        __bf16* dst = Ebf + ((size_t)(bn*64 + lane))*EDIM;
        #pragma unroll
        for (int t = 0; t < 4; ++t)
            *(bf16x8*)(dst + 8*t) = *(bf16x8*)(row + 8*t);
    } else {                               // ---- embed ----
        const int bn = blk - 512;
        __shared__ float xs[FIN];
        if (lane < FIN) xs[lane] = X[bn*FIN + lane];
        __syncthreads();
        float acc = b_embed[lane];
        #pragma unroll
        for (int k = 0; k < FIN; ++k)
            acc = fmaf(xs[k], W_embed[k*Fv + lane], acc);
        H0[bn*Fv + lane] = fmaxf(acc, 0.f);
    }
}

// ---------------------------------------------------------------------------
// Message phase via MFMA. grid = (B*N, 4), 256 threads = 4 waves.
// Block (bn,q) computes agg[bn, q*16 .. q*16+15]; wave w handles
// i = q*16 + w*4 + {0..3}. Fast path (Mt<=2) hoists the epilogue H values
// into 32 registers; bias rides the MFMA C-operand.
// ---------------------------------------------------------------------------
template<int MTN>
__device__ __forceinline__ void msg_body(
    int bn, int q, int w, int lane,
    const __bf16* __restrict__ Wf, const float* __restrict__ b_edge,
    const __bf16* __restrict__ Ebf, const float (*h_src)[66],
    float* __restrict__ agg_g)
{
    const int c16 = lane & 15;
    const int rg  = (lane >> 4) * 4;
    const int kb  = (lane >> 4) * 8;

    bf16x8 af[MTN];
    #pragma unroll
    for (int mt = 0; mt < MTN; ++mt)
        af[mt] = *(const bf16x8*)(Ebf + ((size_t)(bn*64 + mt*16 + c16))*EDIM + kb);

    float hr[4][MTN][4];                   // all indices compile-time (rule #20)
    #pragma unroll
    for (int u = 0; u < 4; ++u)
        #pragma unroll
        for (int mt = 0; mt < MTN; ++mt)
            #pragma unroll
            for (int r = 0; r < 4; ++r)
                hr[u][mt][r] = h_src[mt*16 + rg + r][u*16 + c16];

    #pragma unroll 1
    for (int s = 0; s < 4; ++s) {
        const int i = q*16 + w*4 + s;
        float part = 0.f;
        #pragma unroll
        for (int u = 0; u < 4; ++u) {
            const int nt = i*4 + u;
            const bf16x8 bf = *(const bf16x8*)(Wf + ((size_t)(nt*64 + lane))*8);
            const float  be = b_edge[nt*16 + c16];
            f32x4 cb; cb[0] = be; cb[1] = be; cb[2] = be; cb[3] = be;
            #pragma unroll
            for (int mt = 0; mt < MTN; ++mt) {
                f32x4 d = __builtin_amdgcn_mfma_f32_16x16x32_bf16(af[mt], bf, cb, 0, 0, 0);
                part = fmaf(fmaxf(d[0], 0.f), hr[u][mt][0], part);
                part = fmaf(fmaxf(d[1], 0.f), hr[u][mt][1], part);
                part = fmaf(fmaxf(d[2], 0.f), hr[u][mt][2], part);
                part = fmaf(fmaxf(d[3], 0.f), hr[u][mt][3], part);
            }
        }
        #pragma unroll
        for (int off = 32; off > 0; off >>= 1)
            part += __shfl_xor(part, off);
        if (lane == 0) agg_g[bn*Fv + i] = part;
    }
}

__global__ __launch_bounds__(256, 4) void msg_kernel(
    const float* __restrict__ Hin, const __bf16* __restrict__ Wf,
    const float* __restrict__ b_edge, const __bf16* __restrict__ Ebf,
    const int* __restrict__ m_list_g, const int* __restrict__ cnt_g,
    float* __restrict__ agg_g)
{
    const int bn   = blockIdx.x;
    const int q    = blockIdx.y;
    const int b    = bn >> 6;
    const int tid  = threadIdx.x;
    const int w    = tid >> 6;
    const int lane = tid & 63;

    __shared__ float h_src[Nv][66];

    const int cnt = cnt_g[bn];
    const int Mt  = (cnt + 15) >> 4;       // 0..4 M-tiles (block-uniform)
    const int rows = (Mt <= 2) ? 32 : 64;  // staged row count

    const int* ml = m_list_g + bn*64;
    for (int idx = tid; idx < rows*Fv; idx += 256) {
        int a = idx >> 6, j = idx & 63;
        h_src[a][j] = (a < cnt) ? Hin[(b*Nv + ml[a])*Fv + j] : 0.f;
    }
    __syncthreads();

    if (Mt <= 1)      msg_body<1>(bn, q, w, lane, Wf, b_edge, Ebf, h_src, agg_g);
    else if (Mt == 2) msg_body<2>(bn, q, w, lane, Wf, b_edge, Ebf, h_src, agg_g);
    else {
        // rare general path (cnt > 32): runtime MT loop, LDS-read epilogue
        const int c16 = lane & 15;
        const int rg  = (lane >> 4) * 4;
        const int kb  = (lane >> 4) * 8;
        #pragma unroll 1
        for (int s = 0; s < 4; ++s) {
            const int i = q*16 + w*4 + s;
            float part = 0.f;
            #pragma unroll 1
            for (int u = 0; u < 4; ++u) {
                const int nt = i*4 + u;
                const bf16x8 bf = *(const bf16x8*)(Wf + ((size_t)(nt*64 + lane))*8);
                const float  be = b_edge[nt*16 + c16];
                f32x4 cb; cb[0] = be; cb[1] = be; cb[2] = be; cb[3] = be;
                const int j = u*16 + c16;
                for (int mt = 0; mt < Mt; ++mt) {
                    const bf16x8 a_ = *(const bf16x8*)(Ebf + ((size_t)(bn*64 + mt*16 + c16))*EDIM + kb);
                    f32x4 d = __builtin_amdgcn_mfma_f32_16x16x32_bf16(a_, bf, cb, 0, 0, 0);
                    const int ab = mt*16 + rg;
                    part = fmaf(fmaxf(d[0], 0.f), h_src[ab+0][j], part);
                    part = fmaf(fmaxf(d[1], 0.f), h_src[ab+1][j], part);
                    part = fmaf(fmaxf(d[2], 0.f), h_src[ab+2][j], part);
                    part = fmaf(fmaxf(d[3], 0.f), h_src[ab+3][j], part);
                }
            }
            #pragma unroll
            for (int off = 32; off > 0; off >>= 1)
                part += __shfl_xor(part, off);
            if (lane == 0) agg_g[bn*Fv + i] = part;
        }
    }
}

// ---------------------------------------------------------------------------
// Both GRU steps for one round. grid = B*N blocks, 192 threads.
// 4-way split dot chains for latency hiding at 1 block/CU.
// ---------------------------------------------------------------------------
__global__ __launch_bounds__(192) void gru_kernel(
    const float* __restrict__ Hin, const float* __restrict__ agg_g,
    float* __restrict__ Hout,
    const float* __restrict__ gk, const float* __restrict__ grk,
    const float* __restrict__ gb, const float* __restrict__ grb)
{
    const int bn  = blockIdx.x;
    const int tid = threadIdx.x;   // 0..191

    __shared__ float h_old[Fv];
    __shared__ float aggs[Fv];
    __shared__ float h1[Fv];
    __shared__ float xg[3*Fv];
    __shared__ float hg[3*Fv];

    if (tid < Fv) {
        h_old[tid] = Hin[bn*Fv + tid];
        aggs[tid]  = agg_g[bn*Fv + tid];
    }
    __syncthreads();

    // step 1: h = 0, x = h_old (recurrent side is just the bias)
    {
        float a0 = 0.f, a1 = 0.f, a2 = 0.f, a3 = 0.f;
        #pragma unroll
        for (int k = 0; k < 16; ++k) {
            a0 = fmaf(h_old[k],      gk[(k     )*192 + tid], a0);
            a1 = fmaf(h_old[k + 16], gk[(k + 16)*192 + tid], a1);
            a2 = fmaf(h_old[k + 32], gk[(k + 32)*192 + tid], a2);
            a3 = fmaf(h_old[k + 48], gk[(k + 48)*192 + tid], a3);
        }
        xg[tid] = gb[tid] + ((a0 + a1) + (a2 + a3));
    }
    __syncthreads();
    if (tid < Fv) {
        float z    = sigmoidf_(xg[tid]       + grb[tid]);
        float r    = sigmoidf_(xg[64 + tid]  + grb[64 + tid]);
        float cand = tanhf    (xg[128 + tid] + r * grb[128 + tid]);
        h1[tid] = (1.f - z) * cand;          // z*h + (1-z)*cand with h=0
    }
    __syncthreads();

    // step 2: h = h1, x = agg
    {
        float x0 = 0.f, x1 = 0.f, x2 = 0.f, x3 = 0.f;
        float y0 = 0.f, y1 = 0.f, y2 = 0.f, y3 = 0.f;
        #pragma unroll
        for (int k = 0; k < 16; ++k) {
            x0 = fmaf(aggs[k],      gk [(k     )*192 + tid], x0);
            x1 = fmaf(aggs[k + 16], gk [(k + 16)*192 + tid], x1);
            x2 = fmaf(aggs[k + 32], gk [(k + 32)*192 + tid], x2);
            x3 = fmaf(aggs[k + 48], gk [(k + 48)*192 + tid], x3);
            y0 = fmaf(h1[k],        grk[(k     )*192 + tid], y0);
            y1 = fmaf(h1[k + 16],   grk[(k + 16)*192 + tid], y1);
            y2 = fmaf(h1[k + 32],   grk[(k + 32)*192 + tid], y2);
            y3 = fmaf(h1[k + 48],   grk[(k + 48)*192 + tid], y3);
        }
        xg[tid] = gb[tid]  + ((x0 + x1) + (x2 + x3));
        hg[tid] = grb[tid] + ((y0 + y1) + (y2 + y3));
    }
    __syncthreads();
    if (tid < Fv) {
        float z    = sigmoidf_(xg[tid]       + hg[tid]);
        float r    = sigmoidf_(xg[64 + tid]  + hg[64 + tid]);
        float cand = tanhf    (xg[128 + tid] + r * hg[128 + tid]);
        Hout[bn*Fv + tid] = z * h1[tid] + (1.f - z) * cand;
    }
}

extern "C" void kernel_launch(void* const* d_in, const int* in_sizes, int n_in,
                              void* d_out, int out_size, void* d_ws, size_t ws_size,
                              hipStream_t stream)
{
    const float* X       = (const float*)d_in[0];
    const float* A       = (const float*)d_in[1];
    const float* E       = (const float*)d_in[2];
    const float* W_embed = (const float*)d_in[3];
    const float* b_embed = (const float*)d_in[4];
    const float* W_edge  = (const float*)d_in[5];
    const float* b_edge  = (const float*)d_in[6];
    const float* gk      = (const float*)d_in[7];
    const float* grk     = (const float*)d_in[8];
    const float* gb      = (const float*)d_in[9];
    const float* grb     = (const float*)d_in[10];
    float* out = (float*)d_out;

    float*  H0 = (float*)d_ws;                     // 64 KB
    float*  H1 = H0 + Bv*Nv*Fv;                    // 64 KB
    __bf16* Wf = (__bf16*)(H1 + Bv*Nv*Fv);         // 256 KB
    __bf16* Ebf = Wf + 256*64*8;                   // 1 MB
    int*    m_list_g = (int*)(Ebf + (size_t)Bv*Nv*64*EDIM);  // 64 KB
    int*    cnt_g = m_list_g + Bv*Nv*64;           // 1 KB   (total ~1.45 MB)

    const dim3 mgrid(Bv*Nv, 4);

    prep_kernel<<<768, 64, 0, stream>>>(X, W_embed, b_embed, A, E, W_edge,
                                        H0, Wf, Ebf, m_list_g, cnt_g);

    // round 1: H0 -> H1, agg scratch = out (dead until the end)
    msg_kernel<<<mgrid, 256, 0, stream>>>(H0, Wf, b_edge, Ebf, m_list_g, cnt_g, out);
    gru_kernel<<<Bv*Nv, 192, 0, stream>>>(H0, out, H1, gk, grk, gb, grb);
    // round 2: H1 -> H0, agg scratch = out
    msg_kernel<<<mgrid, 256, 0, stream>>>(H1, Wf, b_edge, Ebf, m_list_g, cnt_g, out);
    gru_kernel<<<Bv*Nv, 192, 0, stream>>>(H1, out, H0, gk, grk, gb, grb);
    // round 3: H0 -> out, agg scratch = H1 (dead after round 2)
    msg_kernel<<<mgrid, 256, 0, stream>>>(H0, Wf, b_edge, Ebf, m_list_g, cnt_g, H1);
    gru_kernel<<<Bv*Nv, 192, 0, stream>>>(H0, H1, out, gk, grk, gb, grb);
}

// Round 6
// 48.558 us; speedup vs baseline: 4.1308x; 1.0258x over previous
//
#include <hip/hip_runtime.h>
#include <math.h>

// Problem constants (B, N, F_IN, E_DIM, F, T) = (4, 64, 32, 32, 64, 3)
#define Bv   4
#define Nv   64
#define FIN  32
#define EDIM 32
#define Fv   64
#define NN   (Nv*Nv)
#define ZROW 256            // sentinel H row (always zero) for padded edges

typedef __bf16 bf16x8 __attribute__((ext_vector_type(8)));
typedef float  f32x4  __attribute__((ext_vector_type(4)));

__device__ __forceinline__ float sigmoidf_(float x) {
    return 1.f / (1.f + __expf(-x));
}

// ---------------------------------------------------------------------------
// One-time prep, fused: grid 768 x 64 threads.
//   blk <  256 : W_edge -> bf16 B-fragments Wf[nt*64+lane][8]
//                (blk 0 also zeroes the sentinel row of H0 and H1)
//   blk <  512 : per-node edge list (as GLOBAL H-row ids, pad->ZROW) and
//                E -> bf16 A-fragment rows (zero-padded) Ebf[bn][64][32]
//   blk >= 512 : embed  H0 = relu(X @ W_embed + b_embed)
// ---------------------------------------------------------------------------
__global__ __launch_bounds__(64) void prep_kernel(
    const float* __restrict__ X, const float* __restrict__ W_embed,
    const float* __restrict__ b_embed, const float* __restrict__ A,
    const float* __restrict__ E, const float* __restrict__ W_edge,
    float* __restrict__ H0, float* __restrict__ H1,
    __bf16* __restrict__ Wf, __bf16* __restrict__ Ebf,
    int* __restrict__ ml_g, int* __restrict__ cnt_g)
{
    const int blk  = blockIdx.x;
    const int lane = threadIdx.x;

    if (blk < 256) {                       // ---- W_edge fragments ----
        const int nt = blk;
        const int kb = (lane >> 4) * 8;
        const int c  = nt*16 + (lane & 15);
        bf16x8 v;
        #pragma unroll
        for (int t = 0; t < 8; ++t)
            v[t] = (__bf16)W_edge[(kb + t)*4096 + c];
        *(bf16x8*)(Wf + ((size_t)(nt*64 + lane))*8) = v;
        if (blk == 0) {                    // zero sentinel rows
            H0[ZROW*Fv + lane] = 0.f;
            H1[ZROW*Fv + lane] = 0.f;
        }
    } else if (blk < 512) {                // ---- edge list + E rows ----
        const int bn = blk - 256;
        const int b  = bn >> 6;
        const int n  = bn & 63;
        __shared__ int ml[Nv];
        __shared__ int cnt_s;
        if (lane == 0) {                   // serial scan: once, off hot path
            int c = 0;
            const float* arow = A + b*NN + n*Nv;
            for (int m = 0; m < Nv; ++m)
                if (arow[m] != 0.f) ml[c++] = m;
            cnt_s = c;
        }
        __syncthreads();
        const int cnt = cnt_s;
        ml_g[bn*64 + lane] = (lane < cnt) ? (b*Nv + ml[lane]) : ZROW;
        if (lane == 0) cnt_g[bn] = cnt;
        __bf16 row[EDIM];
        if (lane < cnt) {
            const float* er = E + ((size_t)(b*NN + n*Nv + ml[lane]))*EDIM;
            #pragma unroll
            for (int t = 0; t < 8; ++t) {
                const float4 x = *(const float4*)(er + 4*t);
                row[4*t  ] = (__bf16)x.x; row[4*t+1] = (__bf16)x.y;
                row[4*t+2] = (__bf16)x.z; row[4*t+3] = (__bf16)x.w;
            }
        } else {
            #pragma unroll
            for (int e = 0; e < EDIM; ++e) row[e] = (__bf16)0.f;
        }
        __bf16* dst = Ebf + ((size_t)(bn*64 + lane))*EDIM;
        #pragma unroll
        for (int t = 0; t < 4; ++t)
            *(bf16x8*)(dst + 8*t) = *(bf16x8*)(row + 8*t);
    } else {                               // ---- embed ----
        const int bn = blk - 512;
        __shared__ float xs[FIN];
        if (lane < FIN) xs[lane] = X[bn*FIN + lane];
        __syncthreads();
        float acc = b_embed[lane];
        #pragma unroll
        for (int k = 0; k < FIN; ++k)
            acc = fmaf(xs[k], W_embed[k*Fv + lane], acc);
        H0[bn*Fv + lane] = fmaxf(acc, 0.f);
    }
}

// ---------------------------------------------------------------------------
// Message phase via MFMA — LDS-free, barrier-free.
// grid = (B*N, 8), 256 threads = 4 waves. Wave w of block (bn,qq) owns
// i0 = qq*8 + w*2 and i0+1. u-outer loop: h values (L1-hot gathered Hin
// reads via sentinel-padded global row ids) loaded once per u, reused by
// both i-slices; bias rides the MFMA C-operand.
// ---------------------------------------------------------------------------
template<int MTN>
__device__ __forceinline__ void msg_body(
    int bn, int qq, int w, int lane,
    const float* __restrict__ Hin, const __bf16* __restrict__ Wf,
    const float* __restrict__ b_edge, const __bf16* __restrict__ Ebf,
    const int* __restrict__ ml_g, float* __restrict__ agg_g)
{
    const int c16 = lane & 15;
    const int rg  = (lane >> 4) * 4;
    const int kb  = (lane >> 4) * 8;

    bf16x8 af[MTN];
    int4   ri[MTN];
    #pragma unroll
    for (int mt = 0; mt < MTN; ++mt) {
        af[mt] = *(const bf16x8*)(Ebf + ((size_t)(bn*64 + mt*16 + c16))*EDIM + kb);
        ri[mt] = *(const int4*)(ml_g + bn*64 + mt*16 + rg);
    }

    const int i0 = qq*8 + w*2;
    float p0 = 0.f, p1 = 0.f;

    #pragma unroll
    for (int u = 0; u < 4; ++u) {
        const int jc = u*16 + c16;
        float hu[MTN][4];
        #pragma unroll
        for (int mt = 0; mt < MTN; ++mt) {
            hu[mt][0] = Hin[ri[mt].x*Fv + jc];
            hu[mt][1] = Hin[ri[mt].y*Fv + jc];
            hu[mt][2] = Hin[ri[mt].z*Fv + jc];
            hu[mt][3] = Hin[ri[mt].w*Fv + jc];
        }
        #pragma unroll
        for (int ii = 0; ii < 2; ++ii) {
            const int nt = (i0 + ii)*4 + u;
            const bf16x8 bf = *(const bf16x8*)(Wf + ((size_t)(nt*64 + lane))*8);
            const float  be = b_edge[nt*16 + c16];
            f32x4 cb; cb[0] = be; cb[1] = be; cb[2] = be; cb[3] = be;
            float acc = 0.f;
            #pragma unroll
            for (int mt = 0; mt < MTN; ++mt) {
                f32x4 d = __builtin_amdgcn_mfma_f32_16x16x32_bf16(af[mt], bf, cb, 0, 0, 0);
                acc = fmaf(fmaxf(d[0], 0.f), hu[mt][0], acc);
                acc = fmaf(fmaxf(d[1], 0.f), hu[mt][1], acc);
                acc = fmaf(fmaxf(d[2], 0.f), hu[mt][2], acc);
                acc = fmaf(fmaxf(d[3], 0.f), hu[mt][3], acc);
            }
            if (ii == 0) p0 += acc; else p1 += acc;
        }
    }
    #pragma unroll
    for (int off = 32; off > 0; off >>= 1) {
        p0 += __shfl_xor(p0, off);
        p1 += __shfl_xor(p1, off);
    }
    if (lane == 0) {
        agg_g[bn*Fv + i0]     = p0;
        agg_g[bn*Fv + i0 + 1] = p1;
    }
}

__global__ __launch_bounds__(256) void msg_kernel(
    const float* __restrict__ Hin, const __bf16* __restrict__ Wf,
    const float* __restrict__ b_edge, const __bf16* __restrict__ Ebf,
    const int* __restrict__ ml_g, const int* __restrict__ cnt_g,
    float* __restrict__ agg_g)
{
    const int bn   = blockIdx.x;
    const int qq   = blockIdx.y;
    const int tid  = threadIdx.x;
    const int w    = tid >> 6;
    const int lane = tid & 63;

    const int cnt = cnt_g[bn];
    const int Mt  = (cnt == 0) ? 1 : ((cnt + 15) >> 4);   // block-uniform

    if (Mt <= 1) {
        msg_body<1>(bn, qq, w, lane, Hin, Wf, b_edge, Ebf, ml_g, agg_g);
    } else if (Mt == 2) {
        msg_body<2>(bn, qq, w, lane, Hin, Wf, b_edge, Ebf, ml_g, agg_g);
    } else {
        // rare path (cnt > 32): runtime mt loop, minimal live registers
        const int c16 = lane & 15;
        const int rg  = (lane >> 4) * 4;
        const int kb  = (lane >> 4) * 8;
        const int i0  = qq*8 + w*2;
        #pragma unroll
        for (int ii = 0; ii < 2; ++ii) {
            float part = 0.f;
            #pragma unroll 1
            for (int u = 0; u < 4; ++u) {
                const int jc = u*16 + c16;
                const int nt = (i0 + ii)*4 + u;
                const bf16x8 bf = *(const bf16x8*)(Wf + ((size_t)(nt*64 + lane))*8);
                const float  be = b_edge[nt*16 + c16];
                f32x4 cb; cb[0] = be; cb[1] = be; cb[2] = be; cb[3] = be;
                for (int mt = 0; mt < Mt; ++mt) {
                    const bf16x8 a_ = *(const bf16x8*)(Ebf + ((size_t)(bn*64 + mt*16 + c16))*EDIM + kb);
                    const int4 ri = *(const int4*)(ml_g + bn*64 + mt*16 + rg);
                    f32x4 d = __builtin_amdgcn_mfma_f32_16x16x32_bf16(a_, bf, cb, 0, 0, 0);
                    part = fmaf(fmaxf(d[0], 0.f), Hin[ri.x*Fv + jc], part);
                    part = fmaf(fmaxf(d[1], 0.f), Hin[ri.y*Fv + jc], part);
                    part = fmaf(fmaxf(d[2], 0.f), Hin[ri.z*Fv + jc], part);
                    part = fmaf(fmaxf(d[3], 0.f), Hin[ri.w*Fv + jc], part);
                }
            }
            #pragma unroll
            for (int off = 32; off > 0; off >>= 1)
                part += __shfl_xor(part, off);
            if (lane == 0) agg_g[bn*Fv + i0 + ii] = part;
        }
    }
}

// ---------------------------------------------------------------------------
// Both GRU steps for one round. grid = B*N blocks, 192 threads.
// ---------------------------------------------------------------------------
__global__ __launch_bounds__(192) void gru_kernel(
    const float* __restrict__ Hin, const float* __restrict__ agg_g,
    float* __restrict__ Hout,
    const float* __restrict__ gk, const float* __restrict__ grk,
    const float* __restrict__ gb, const float* __restrict__ grb)
{
    const int bn  = blockIdx.x;
    const int tid = threadIdx.x;   // 0..191

    __shared__ float h_old[Fv];
    __shared__ float aggs[Fv];
    __shared__ float h1[Fv];
    __shared__ float xg[3*Fv];
    __shared__ float hg[3*Fv];

    if (tid < Fv) {
        h_old[tid] = Hin[bn*Fv + tid];
        aggs[tid]  = agg_g[bn*Fv + tid];
    }
    __syncthreads();

    // step 1: h = 0, x = h_old (recurrent side is just the bias)
    {
        float a0 = 0.f, a1 = 0.f, a2 = 0.f, a3 = 0.f;
        #pragma unroll
        for (int k = 0; k < 16; ++k) {
            a0 = fmaf(h_old[k],      gk[(k     )*192 + tid], a0);
            a1 = fmaf(h_old[k + 16], gk[(k + 16)*192 + tid], a1);
            a2 = fmaf(h_old[k + 32], gk[(k + 32)*192 + tid], a2);
            a3 = fmaf(h_old[k + 48], gk[(k + 48)*192 + tid], a3);
        }
        xg[tid] = gb[tid] + ((a0 + a1) + (a2 + a3));
    }
    __syncthreads();
    if (tid < Fv) {
        float z    = sigmoidf_(xg[tid]       + grb[tid]);
        float r    = sigmoidf_(xg[64 + tid]  + grb[64 + tid]);
        float cand = tanhf    (xg[128 + tid] + r * grb[128 + tid]);
        h1[tid] = (1.f - z) * cand;          // z*h + (1-z)*cand with h=0
    }
    __syncthreads();

    // step 2: h = h1, x = agg
    {
        float x0 = 0.f, x1 = 0.f, x2 = 0.f, x3 = 0.f;
        float y0 = 0.f, y1 = 0.f, y2 = 0.f, y3 = 0.f;
        #pragma unroll
        for (int k = 0; k < 16; ++k) {
            x0 = fmaf(aggs[k],      gk [(k     )*192 + tid], x0);
            x1 = fmaf(aggs[k + 16], gk [(k + 16)*192 + tid], x1);
            x2 = fmaf(aggs[k + 32], gk [(k + 32)*192 + tid], x2);
            x3 = fmaf(aggs[k + 48], gk [(k + 48)*192 + tid], x3);
            y0 = fmaf(h1[k],        grk[(k     )*192 + tid], y0);
            y1 = fmaf(h1[k + 16],   grk[(k + 16)*192 + tid], y1);
            y2 = fmaf(h1[k + 32],   grk[(k + 32)*192 + tid], y2);
            y3 = fmaf(h1[k + 48],   grk[(k + 48)*192 + tid], y3);
        }
        xg[tid] = gb[tid]  + ((x0 + x1) + (x2 + x3));
        hg[tid] = grb[tid] + ((y0 + y1) + (y2 + y3));
    }
    __syncthreads();
    if (tid < Fv) {
        float z    = sigmoidf_(xg[tid]       + hg[tid]);
        float r    = sigmoidf_(xg[64 + tid]  + hg[64 + tid]);
        float cand = tanhf    (xg[128 + tid] + r * hg[128 + tid]);
        Hout[bn*Fv + tid] = z * h1[tid] + (1.f - z) * cand;
    }
}

extern "C" void kernel_launch(void* const* d_in, const int* in_sizes, int n_in,
                              void* d_out, int out_size, void* d_ws, size_t ws_size,
                              hipStream_t stream)
{
    const float* X       = (const float*)d_in[0];
    const float* A       = (const float*)d_in[1];
    const float* E       = (const float*)d_in[2];
    const float* W_embed = (const float*)d_in[3];
    const float* b_embed = (const float*)d_in[4];
    const float* W_edge  = (const float*)d_in[5];
    const float* b_edge  = (const float*)d_in[6];
    const float* gk      = (const float*)d_in[7];
    const float* grk     = (const float*)d_in[8];
    const float* gb      = (const float*)d_in[9];
    const float* grb     = (const float*)d_in[10];
    float* out = (float*)d_out;

    // ws layout (floats unless noted); H0/H1 have 257 rows (row 256 = zeros)
    float*  H0  = (float*)d_ws;                       // 257*64 floats
    float*  H1  = H0 + (ZROW + 1)*Fv;                 // 257*64 floats
    __bf16* Wf  = (__bf16*)(H1 + (ZROW + 1)*Fv);      // 256 KB
    __bf16* Ebf = Wf + 256*64*8;                      // 1 MB
    int*    ml_g  = (int*)(Ebf + (size_t)Bv*Nv*64*EDIM); // 64 KB
    int*    cnt_g = ml_g + Bv*Nv*64;                  // 1 KB

    const dim3 mgrid(Bv*Nv, 8);

    prep_kernel<<<768, 64, 0, stream>>>(X, W_embed, b_embed, A, E, W_edge,
                                        H0, H1, Wf, Ebf, ml_g, cnt_g);

    // round 1: H0 -> H1, agg scratch = out (dead until the end)
    msg_kernel<<<mgrid, 256, 0, stream>>>(H0, Wf, b_edge, Ebf, ml_g, cnt_g, out);
    gru_kernel<<<Bv*Nv, 192, 0, stream>>>(H0, out, H1, gk, grk, gb, grb);
    // round 2: H1 -> H0, agg scratch = out
    msg_kernel<<<mgrid, 256, 0, stream>>>(H1, Wf, b_edge, Ebf, ml_g, cnt_g, out);
    gru_kernel<<<Bv*Nv, 192, 0, stream>>>(H1, out, H0, gk, grk, gb, grb);
    // round 3: H0 -> out, agg scratch = H1 (dead after round 2)
    msg_kernel<<<mgrid, 256, 0, stream>>>(H0, Wf, b_edge, Ebf, ml_g, cnt_g, H1);
    gru_kernel<<<Bv*Nv, 192, 0, stream>>>(H0, H1, out, gk, grk, gb, grb);
}